// Round 2
// baseline (481.151 us; speedup 1.0000x reference)
//
#include <hip/hip_runtime.h>

#define DIM 33
#define D2 (DIM * DIM)          // 1089
#define NENT (DIM * DIM * DIM)  // 35937
#define HW 2073600              // 1920*1080
#define NIMG 8

typedef _Float16 half8 __attribute__((ext_vector_type(8)));
typedef float f32x4 __attribute__((ext_vector_type(4)));

// Packed entry e=(b*33+g)*33+r, 32 bytes (two half8):
//  A[0..5] = row(b,g):   c0(r) c1(r) c2(r) c0(r+1) c1(r+1) c2(r+1)
//  A[6..7] = row(b,g+1): c0(r) c1(r)
//  B[0..3] = row(b,g+1): c2(r) c0(r+1) c1(r+1) c2(r+1)
//  B[4..7] = pad
__global__ __launch_bounds__(256) void build_packed(const float* __restrict__ lut,
                                                    half8* __restrict__ P) {
    int e = blockIdx.x * 256 + threadIdx.x;
    if (e >= NENT) return;
    int r = e % DIM;
    int t = e / DIM;
    int g = t % DIM;
    int b = t / DIM;
    int r1 = min(r + 1, DIM - 1);
    int g1 = min(g + 1, DIM - 1);
    int i00 = (b * DIM + g) * DIM;
    int i01 = (b * DIM + g1) * DIM;
    half8 A, B;
    A[0] = (_Float16)lut[0 * NENT + i00 + r];
    A[1] = (_Float16)lut[1 * NENT + i00 + r];
    A[2] = (_Float16)lut[2 * NENT + i00 + r];
    A[3] = (_Float16)lut[0 * NENT + i00 + r1];
    A[4] = (_Float16)lut[1 * NENT + i00 + r1];
    A[5] = (_Float16)lut[2 * NENT + i00 + r1];
    A[6] = (_Float16)lut[0 * NENT + i01 + r];
    A[7] = (_Float16)lut[1 * NENT + i01 + r];
    B[0] = (_Float16)lut[2 * NENT + i01 + r];
    B[1] = (_Float16)lut[0 * NENT + i01 + r1];
    B[2] = (_Float16)lut[1 * NENT + i01 + r1];
    B[3] = (_Float16)lut[2 * NENT + i01 + r1];
    B[4] = (_Float16)0.f;
    B[5] = (_Float16)0.f;
    B[6] = (_Float16)0.f;
    B[7] = (_Float16)0.f;
    P[2 * e]     = A;
    P[2 * e + 1] = B;
}

__device__ __forceinline__ float lerpf(float a, float b, float t) {
    return fmaf(t, b - a, a);
}

__global__ __launch_bounds__(256) void lut3d_main(const float* __restrict__ x,
                                                  const half8* __restrict__ P,
                                                  float* __restrict__ out) {
    const int img = blockIdx.y;
    const int i = (blockIdx.x * 256 + threadIdx.x) * 4;
    const float* xp = x + (size_t)img * 3 * HW + i;
    f32x4 Rv = __builtin_nontemporal_load((const f32x4*)xp);
    f32x4 Gv = __builtin_nontemporal_load((const f32x4*)(xp + HW));
    f32x4 Bv = __builtin_nontemporal_load((const f32x4*)(xp + 2 * HW));
    float o0[4], o1[4], o2[4];
    const float inv = 32.0f / 1.000001f;
#pragma unroll
    for (int k = 0; k < 4; ++k) {
        float xr = Rv[k] * inv;
        float xg = Gv[k] * inv;
        float xb = Bv[k] * inv;
        // trunc + clamp == floor + clip (inputs are in [0,1), scaled >= 0)
        int ri = (int)xr; ri = ri < 0 ? 0 : (ri > DIM - 2 ? DIM - 2 : ri);
        int gi = (int)xg; gi = gi < 0 ? 0 : (gi > DIM - 2 ? DIM - 2 : gi);
        int bi = (int)xb; bi = bi < 0 ? 0 : (bi > DIM - 2 ? DIM - 2 : bi);
        float rd = xr - (float)ri;
        float gd = xg - (float)gi;
        float bd = xb - (float)bi;
        int base = (bi * DIM + gi) * DIM + ri;
        half8 a0 = P[2 * base];
        half8 a1 = P[2 * base + 1];
        half8 c0 = P[2 * (base + D2)];
        half8 c1 = P[2 * (base + D2) + 1];
        // plane b: lerp along r within each g-row
        float q00_0 = lerpf((float)a0[0], (float)a0[3], rd);
        float q00_1 = lerpf((float)a0[1], (float)a0[4], rd);
        float q00_2 = lerpf((float)a0[2], (float)a0[5], rd);
        float q01_0 = lerpf((float)a0[6], (float)a1[1], rd);
        float q01_1 = lerpf((float)a0[7], (float)a1[2], rd);
        float q01_2 = lerpf((float)a1[0], (float)a1[3], rd);
        float p0_0 = lerpf(q00_0, q01_0, gd);
        float p0_1 = lerpf(q00_1, q01_1, gd);
        float p0_2 = lerpf(q00_2, q01_2, gd);
        // plane b+1
        float s00_0 = lerpf((float)c0[0], (float)c0[3], rd);
        float s00_1 = lerpf((float)c0[1], (float)c0[4], rd);
        float s00_2 = lerpf((float)c0[2], (float)c0[5], rd);
        float s01_0 = lerpf((float)c0[6], (float)c1[1], rd);
        float s01_1 = lerpf((float)c0[7], (float)c1[2], rd);
        float s01_2 = lerpf((float)c1[0], (float)c1[3], rd);
        float p1_0 = lerpf(s00_0, s01_0, gd);
        float p1_1 = lerpf(s00_1, s01_1, gd);
        float p1_2 = lerpf(s00_2, s01_2, gd);
        o0[k] = lerpf(p0_0, p1_0, bd);
        o1[k] = lerpf(p0_1, p1_1, bd);
        o2[k] = lerpf(p0_2, p1_2, bd);
    }
    float* op = out + (size_t)img * 3 * HW + i;
    f32x4 v0 = {o0[0], o0[1], o0[2], o0[3]};
    f32x4 v1 = {o1[0], o1[1], o1[2], o1[3]};
    f32x4 v2 = {o2[0], o2[1], o2[2], o2[3]};
    __builtin_nontemporal_store(v0, (f32x4*)op);
    __builtin_nontemporal_store(v1, (f32x4*)(op + HW));
    __builtin_nontemporal_store(v2, (f32x4*)(op + 2 * HW));
}

// Fallback if workspace is too small for the packed table: direct fp32 gathers.
__global__ __launch_bounds__(256) void lut3d_direct(const float* __restrict__ x,
                                                    const float* __restrict__ lut,
                                                    float* __restrict__ out) {
    const int img = blockIdx.y;
    const int i = (blockIdx.x * 256 + threadIdx.x) * 4;
    const float* xp = x + (size_t)img * 3 * HW + i;
    f32x4 Rv = *(const f32x4*)xp;
    f32x4 Gv = *(const f32x4*)(xp + HW);
    f32x4 Bv = *(const f32x4*)(xp + 2 * HW);
    float o0[4], o1[4], o2[4];
    const float inv = 32.0f / 1.000001f;
#pragma unroll
    for (int k = 0; k < 4; ++k) {
        float xr = Rv[k] * inv;
        float xg = Gv[k] * inv;
        float xb = Bv[k] * inv;
        int ri = (int)xr; ri = ri < 0 ? 0 : (ri > DIM - 2 ? DIM - 2 : ri);
        int gi = (int)xg; gi = gi < 0 ? 0 : (gi > DIM - 2 ? DIM - 2 : gi);
        int bi = (int)xb; bi = bi < 0 ? 0 : (bi > DIM - 2 ? DIM - 2 : bi);
        float rd = xr - (float)ri;
        float gd = xg - (float)gi;
        float bd = xb - (float)bi;
        int base = (bi * DIM + gi) * DIM + ri;
        float oc[3];
#pragma unroll
        for (int c = 0; c < 3; ++c) {
            const float* L = lut + c * NENT + base;
            float v000 = L[0],        v001 = L[1];
            float v010 = L[DIM],      v011 = L[DIM + 1];
            float v100 = L[D2],       v101 = L[D2 + 1];
            float v110 = L[D2 + DIM], v111 = L[D2 + DIM + 1];
            float q0 = lerpf(v000, v001, rd);
            float q1 = lerpf(v010, v011, rd);
            float q2 = lerpf(v100, v101, rd);
            float q3 = lerpf(v110, v111, rd);
            float p0 = lerpf(q0, q1, gd);
            float p1 = lerpf(q2, q3, gd);
            oc[c] = lerpf(p0, p1, bd);
        }
        o0[k] = oc[0]; o1[k] = oc[1]; o2[k] = oc[2];
    }
    float* op = out + (size_t)img * 3 * HW + i;
    f32x4 v0 = {o0[0], o0[1], o0[2], o0[3]};
    f32x4 v1 = {o1[0], o1[1], o1[2], o1[3]};
    f32x4 v2 = {o2[0], o2[1], o2[2], o2[3]};
    *(f32x4*)op = v0;
    *(f32x4*)(op + HW) = v1;
    *(f32x4*)(op + 2 * HW) = v2;
}

extern "C" void kernel_launch(void* const* d_in, const int* in_sizes, int n_in,
                              void* d_out, int out_size, void* d_ws, size_t ws_size,
                              hipStream_t stream) {
    const float* lut = (const float*)d_in[0];
    const float* x   = (const float*)d_in[1];
    float* out = (float*)d_out;

    const dim3 grid(HW / 4 / 256, NIMG);
    const dim3 block(256);

    if (ws_size >= (size_t)NENT * 32) {
        half8* P = (half8*)d_ws;
        build_packed<<<(NENT + 255) / 256, 256, 0, stream>>>(lut, P);
        lut3d_main<<<grid, block, 0, stream>>>(x, P, out);
    } else {
        lut3d_direct<<<grid, block, 0, stream>>>(x, lut, out);
    }
}

// Round 3
// 354.410 us; speedup vs baseline: 1.3576x; 1.3576x over previous
//
#include <hip/hip_runtime.h>
#include <stdint.h>

#define DIM 33
#define D2 (DIM * DIM)          // 1089
#define NENT (DIM * DIM * DIM)  // 35937
#define HW 2073600              // 1920*1080
#define NIMG 8
#define HW4 (HW / 4)            // 518400 quad-pixels per image-channel-plane
#define QP (NIMG * HW4)         // 4147200 total quad-pixels
#define BLK 1024
#define NBLK 256                // one persistent block per CU (LDS-capped anyway)
#define STRIDE (BLK * NBLK)     // 262144

typedef float f32x4 __attribute__((ext_vector_type(4)));

__device__ __forceinline__ float lerpf(float a, float b, float t) {
    return fmaf(t, b - a, a);
}

// 10-10-10 fixed point pack: T[e] = qr | qg<<10 | qb<<20, e=(b*33+g)*33+r
__global__ __launch_bounds__(256) void build_packed10(const float* __restrict__ lut,
                                                      uint32_t* __restrict__ T) {
    int e = blockIdx.x * 256 + threadIdx.x;
    if (e >= NENT) return;
    uint32_t q0 = (uint32_t)(lut[e] * 1023.f + 0.5f);
    uint32_t q1 = (uint32_t)(lut[NENT + e] * 1023.f + 0.5f);
    uint32_t q2 = (uint32_t)(lut[2 * NENT + e] * 1023.f + 0.5f);
    T[e] = q0 | (q1 << 10) | (q2 << 20);
}

#define U0(v) ((float)((v) & 1023u))
#define U1(v) ((float)(((v) >> 10) & 1023u))
#define U2(v) ((float)((v) >> 20))

__global__ __launch_bounds__(1024) void lut3d_lds(const float* __restrict__ x,
                                                  const uint32_t* __restrict__ T,
                                                  float* __restrict__ out) {
    __shared__ uint32_t L[NENT];  // 143,748 B of the 160 KiB LDS
    for (int e = threadIdx.x; e < NENT; e += BLK) L[e] = T[e];
    __syncthreads();

    const float inv = 32.0f / 1.000001f;
    const float qs = 1.0f / 1023.0f;

    int j = blockIdx.x * BLK + threadIdx.x;
    f32x4 R, G, B;
    {
        int img = j / HW4;
        int i = (j - img * HW4) * 4;
        const float* xp = x + (size_t)img * 3 * HW + i;
        R = *(const f32x4*)xp;
        G = *(const f32x4*)(xp + HW);
        B = *(const f32x4*)(xp + 2 * HW);
    }

    while (j < QP) {
        int jn = j + STRIDE;
        f32x4 Rn, Gn, Bn;
        if (jn < QP) {  // prefetch next tile while we gather+compute current
            int img = jn / HW4;
            int i = (jn - img * HW4) * 4;
            const float* xp = x + (size_t)img * 3 * HW + i;
            Rn = *(const f32x4*)xp;
            Gn = *(const f32x4*)(xp + HW);
            Bn = *(const f32x4*)(xp + 2 * HW);
        }

        float o0[4], o1[4], o2[4];
#pragma unroll
        for (int k = 0; k < 4; ++k) {
            float xr = R[k] * inv;
            float xg = G[k] * inv;
            float xb = B[k] * inv;
            // x >= 0, so trunc == floor; only upper clamp needed
            int ri = (int)xr; ri = ri > DIM - 2 ? DIM - 2 : ri;
            int gi = (int)xg; gi = gi > DIM - 2 ? DIM - 2 : gi;
            int bi = (int)xb; bi = bi > DIM - 2 ? DIM - 2 : bi;
            float rd = xr - (float)ri;
            float gd = xg - (float)gi;
            float bd = xb - (float)bi;
            int base = (bi * DIM + gi) * DIM + ri;
            uint32_t v000 = L[base],            v001 = L[base + 1];
            uint32_t v010 = L[base + DIM],      v011 = L[base + DIM + 1];
            uint32_t v100 = L[base + D2],       v101 = L[base + D2 + 1];
            uint32_t v110 = L[base + D2 + DIM], v111 = L[base + D2 + DIM + 1];

            {   // channel 0
                float q00 = lerpf(U0(v000), U0(v001), rd);
                float q01 = lerpf(U0(v010), U0(v011), rd);
                float q10 = lerpf(U0(v100), U0(v101), rd);
                float q11 = lerpf(U0(v110), U0(v111), rd);
                o0[k] = lerpf(lerpf(q00, q01, gd), lerpf(q10, q11, gd), bd) * qs;
            }
            {   // channel 1
                float q00 = lerpf(U1(v000), U1(v001), rd);
                float q01 = lerpf(U1(v010), U1(v011), rd);
                float q10 = lerpf(U1(v100), U1(v101), rd);
                float q11 = lerpf(U1(v110), U1(v111), rd);
                o1[k] = lerpf(lerpf(q00, q01, gd), lerpf(q10, q11, gd), bd) * qs;
            }
            {   // channel 2
                float q00 = lerpf(U2(v000), U2(v001), rd);
                float q01 = lerpf(U2(v010), U2(v011), rd);
                float q10 = lerpf(U2(v100), U2(v101), rd);
                float q11 = lerpf(U2(v110), U2(v111), rd);
                o2[k] = lerpf(lerpf(q00, q01, gd), lerpf(q10, q11, gd), bd) * qs;
            }
        }

        {
            int img = j / HW4;
            int i = (j - img * HW4) * 4;
            float* op = out + (size_t)img * 3 * HW + i;
            f32x4 v0 = {o0[0], o0[1], o0[2], o0[3]};
            f32x4 v1 = {o1[0], o1[1], o1[2], o1[3]};
            f32x4 v2 = {o2[0], o2[1], o2[2], o2[3]};
            __builtin_nontemporal_store(v0, (f32x4*)op);
            __builtin_nontemporal_store(v1, (f32x4*)(op + HW));
            __builtin_nontemporal_store(v2, (f32x4*)(op + 2 * HW));
        }

        R = Rn; G = Gn; B = Bn;
        j = jn;
    }
}

// Fallback if workspace is too small: direct fp32 gathers from global LUT.
__global__ __launch_bounds__(256) void lut3d_direct(const float* __restrict__ x,
                                                    const float* __restrict__ lut,
                                                    float* __restrict__ out) {
    const int img = blockIdx.y;
    const int i = (blockIdx.x * 256 + threadIdx.x) * 4;
    const float* xp = x + (size_t)img * 3 * HW + i;
    f32x4 Rv = *(const f32x4*)xp;
    f32x4 Gv = *(const f32x4*)(xp + HW);
    f32x4 Bv = *(const f32x4*)(xp + 2 * HW);
    float o0[4], o1[4], o2[4];
    const float inv = 32.0f / 1.000001f;
#pragma unroll
    for (int k = 0; k < 4; ++k) {
        float xr = Rv[k] * inv;
        float xg = Gv[k] * inv;
        float xb = Bv[k] * inv;
        int ri = (int)xr; ri = ri < 0 ? 0 : (ri > DIM - 2 ? DIM - 2 : ri);
        int gi = (int)xg; gi = gi < 0 ? 0 : (gi > DIM - 2 ? DIM - 2 : gi);
        int bi = (int)xb; bi = bi < 0 ? 0 : (bi > DIM - 2 ? DIM - 2 : bi);
        float rd = xr - (float)ri;
        float gd = xg - (float)gi;
        float bd = xb - (float)bi;
        int base = (bi * DIM + gi) * DIM + ri;
        float oc[3];
#pragma unroll
        for (int c = 0; c < 3; ++c) {
            const float* Lp = lut + c * NENT + base;
            float v000 = Lp[0],        v001 = Lp[1];
            float v010 = Lp[DIM],      v011 = Lp[DIM + 1];
            float v100 = Lp[D2],       v101 = Lp[D2 + 1];
            float v110 = Lp[D2 + DIM], v111 = Lp[D2 + DIM + 1];
            float q0 = lerpf(v000, v001, rd);
            float q1 = lerpf(v010, v011, rd);
            float q2 = lerpf(v100, v101, rd);
            float q3 = lerpf(v110, v111, rd);
            float p0 = lerpf(q0, q1, gd);
            float p1 = lerpf(q2, q3, gd);
            oc[c] = lerpf(p0, p1, bd);
        }
        o0[k] = oc[0]; o1[k] = oc[1]; o2[k] = oc[2];
    }
    float* op = out + (size_t)img * 3 * HW + i;
    f32x4 v0 = {o0[0], o0[1], o0[2], o0[3]};
    f32x4 v1 = {o1[0], o1[1], o1[2], o1[3]};
    f32x4 v2 = {o2[0], o2[1], o2[2], o2[3]};
    *(f32x4*)op = v0;
    *(f32x4*)(op + HW) = v1;
    *(f32x4*)(op + 2 * HW) = v2;
}

extern "C" void kernel_launch(void* const* d_in, const int* in_sizes, int n_in,
                              void* d_out, int out_size, void* d_ws, size_t ws_size,
                              hipStream_t stream) {
    const float* lut = (const float*)d_in[0];
    const float* x   = (const float*)d_in[1];
    float* out = (float*)d_out;

    if (ws_size >= (size_t)NENT * 4) {
        uint32_t* T = (uint32_t*)d_ws;
        build_packed10<<<(NENT + 255) / 256, 256, 0, stream>>>(lut, T);
        lut3d_lds<<<NBLK, BLK, 0, stream>>>(x, T, out);
    } else {
        const dim3 grid(HW / 4 / 256, NIMG);
        lut3d_direct<<<grid, dim3(256), 0, stream>>>(x, lut, out);
    }
}